// Round 4
// baseline (4913.644 us; speedup 1.0000x reference)
//
#include <hip/hip_runtime.h>
#include <math.h>

// Problem constants
constexpr int DD    = 512;     // D
constexpr int D2    = 1024;    // 2D
constexpr int NTOK  = 256;     // vocab V (unique tokens = unique pipelines)
constexpr int NSYM  = 512;
constexpr int NCON  = 64;
constexpr int VOCAB = 256;
constexpr int BS_TOT = 32 * 512;   // B*S = 16384
constexpr int NDEPTH = 6;
constexpr int NLOOK  = 3;
constexpr float EPSF = 1e-8f;
constexpr float SCALE = 0.044194173824159216f; // 512^-0.5

__device__ inline void fma4(float4& a, const float4& w, float s) {
    a.x += w.x * s; a.y += w.y * s; a.z += w.z * s; a.w += w.w * s;
}

__device__ inline float wave_sum(float x) {
#pragma unroll
    for (int off = 32; off; off >>= 1) x += __shfl_xor(x, off, 64);
    return x;
}

__device__ inline void wave_argmin(float& d, int& i) {
#pragma unroll
    for (int off = 32; off; off >>= 1) {
        float od = __shfl_xor(d, off, 64);
        int   oi = __shfl_xor(i, off, 64);
        if (od < d || (od == d && oi < i)) { d = od; i = oi; }
    }
}

// ---------------- grid barrier (two-level, 512 blocks, agent scope) ----------------
// bar layout: [0..255] 8 sub-counters at stride 32; [256] generation; [257] master count
// All 512 blocks are co-resident by capacity: 34.8KB LDS (4 blocks/CU limit),
// __launch_bounds__(256,2) (>=2 blocks/CU by VGPR), grid 512 = 2/CU on 256 CUs.
__device__ inline void gsync(unsigned* bar) {
    __syncthreads();
    if (threadIdx.x == 0) {
        __threadfence();
        unsigned g = __hip_atomic_load(bar + 256, __ATOMIC_RELAXED, __HIP_MEMORY_SCOPE_AGENT);
        unsigned* sub = bar + (blockIdx.x & 7) * 32;
        unsigned r = __hip_atomic_fetch_add(sub, 1u, __ATOMIC_ACQ_REL, __HIP_MEMORY_SCOPE_AGENT);
        if (r == 63u) {     // last of this sub-group (512/8 = 64)
            __hip_atomic_store(sub, 0u, __ATOMIC_RELAXED, __HIP_MEMORY_SCOPE_AGENT);
            unsigned m = __hip_atomic_fetch_add(bar + 257, 1u, __ATOMIC_ACQ_REL, __HIP_MEMORY_SCOPE_AGENT);
            if (m == 7u) {  // last sub-group
                __hip_atomic_store(bar + 257, 0u, __ATOMIC_RELAXED, __HIP_MEMORY_SCOPE_AGENT);
                __hip_atomic_fetch_add(bar + 256, 1u, __ATOMIC_RELEASE, __HIP_MEMORY_SCOPE_AGENT);
            }
        }
        while (__hip_atomic_load(bar + 256, __ATOMIC_ACQUIRE, __HIP_MEMORY_SCOPE_AGENT) == g) {
            __builtin_amdgcn_s_sleep(1);
        }
        __threadfence();
    }
    __syncthreads();
}

// ---------------- device GEMM tile: 64x64 output, runtime K-chunks, dbuf LDS ----------------
// sm: 8704 floats (sX[2][2176] | sW[2][2176])
__device__ __forceinline__ void d_gemm(const float* __restrict__ WT,
                                       const float* __restrict__ X,
                                       float* __restrict__ P, int N,
                                       int j0, int t0, int k0, int NC, int pslot,
                                       float* __restrict__ sm) {
    constexpr int LDT = 68;
    float* sX = sm;
    float* sW = sm + 2 * 2176;
    int tid = threadIdx.x;
    int jq = tid & 15, tq = tid >> 4;
    int f0 = tid * 2, f1 = f0 + 1;
    int tA0 = f0 >> 3, kqA0 = f0 & 7;
    int tA1 = f1 >> 3, kqA1 = f1 & 7;
    int kwB0 = f0 >> 4, jB0 = f0 & 15;
    int kwB1 = f1 >> 4, jB1 = f1 & 15;
    float4 vx0, vx1, vw0, vw1;
    float4 acc0 = {0,0,0,0}, acc1 = {0,0,0,0}, acc2 = {0,0,0,0}, acc3 = {0,0,0,0};

#define GLOADP(kbase) do { \
        vx0 = *(const float4*)&X[(size_t)(t0 + tA0) * D2 + (kbase) + kqA0 * 4]; \
        vx1 = *(const float4*)&X[(size_t)(t0 + tA1) * D2 + (kbase) + kqA1 * 4]; \
        vw0 = *(const float4*)&WT[(size_t)((kbase) + kwB0) * N + j0 + jB0 * 4]; \
        vw1 = *(const float4*)&WT[(size_t)((kbase) + kwB1) * N + j0 + jB1 * 4]; \
    } while (0)
#define LSTOREP(bufi) do { \
        float* sxB = sX + (bufi) * 2176; float* swB = sW + (bufi) * 2176; \
        sxB[(kqA0 * 4 + 0) * LDT + tA0] = vx0.x; \
        sxB[(kqA0 * 4 + 1) * LDT + tA0] = vx0.y; \
        sxB[(kqA0 * 4 + 2) * LDT + tA0] = vx0.z; \
        sxB[(kqA0 * 4 + 3) * LDT + tA0] = vx0.w; \
        sxB[(kqA1 * 4 + 0) * LDT + tA1] = vx1.x; \
        sxB[(kqA1 * 4 + 1) * LDT + tA1] = vx1.y; \
        sxB[(kqA1 * 4 + 2) * LDT + tA1] = vx1.z; \
        sxB[(kqA1 * 4 + 3) * LDT + tA1] = vx1.w; \
        *(float4*)&swB[kwB0 * LDT + jB0 * 4] = vw0; \
        *(float4*)&swB[kwB1 * LDT + jB1 * 4] = vw1; \
    } while (0)

    GLOADP(k0);
    LSTOREP(0);
    __syncthreads();
    for (int kc = 0; kc < NC; ++kc) {
        if (kc + 1 < NC) GLOADP(k0 + (kc + 1) * 32);
        const float* sxB = sX + (kc & 1) * 2176;
        const float* swB = sW + (kc & 1) * 2176;
#pragma unroll 8
        for (int k = 0; k < 32; ++k) {
            float4 xa = *(const float4*)&sxB[k * LDT + tq * 4];
            float4 wb = *(const float4*)&swB[k * LDT + jq * 4];
            fma4(acc0, wb, xa.x);
            fma4(acc1, wb, xa.y);
            fma4(acc2, wb, xa.z);
            fma4(acc3, wb, xa.w);
        }
        if (kc + 1 < NC) LSTOREP((kc + 1) & 1);
        __syncthreads();
    }
#undef GLOADP
#undef LSTOREP
    size_t base = ((size_t)pslot * NTOK + (t0 + tq * 4)) * N + j0 + jq * 4;
    *(float4*)&P[base]         = acc0;
    *(float4*)&P[base + N]     = acc1;
    *(float4*)&P[base + 2*N]   = acc2;
    *(float4*)&P[base + 3*N]   = acc3;
}

// ---------------- device epilogue: cell combine + tanh-norm ----------------
__device__ __forceinline__ void d_epi(const float* __restrict__ cellP,
                                      float* __restrict__ zo, int ns, int t) {
    int tid = threadIdx.x;
#pragma unroll
    for (int r = 0; r < 2; ++r) {
        int j = r * 256 + tid;
        float lr = 0.f, li = 0.f;
        for (int s = 0; s < ns; ++s) {
            lr += cellP[((size_t)s * NTOK + t) * D2 + j];
            li += cellP[((size_t)s * NTOK + t) * D2 + DD + j];
        }
        float m = sqrtf(lr * lr + li * li + EPSF);
        float inv = 1.0f / (1.0f + m);
        zo[(size_t)t * D2 + j]      = tanhf(lr * inv);
        zo[(size_t)t * D2 + DD + j] = tanhf(li * inv);
    }
}

// ---------------- device attend (token t, 256 threads, 16 QP partials) ----------------
__device__ __forceinline__ void d_attend(float* __restrict__ z,
                                         const float* __restrict__ QP,
                                         const float* __restrict__ qb,
                                         const float* __restrict__ Kmem,
                                         const float* __restrict__ Vmem,
                                         const float* __restrict__ conf,
                                         int M, int v, float* __restrict__ sm) {
    int tid = threadIdx.x;
    int lane = tid & 63, w = tid >> 6;
    float* s_part = sm;   // [4][5]
    float q0 = 0.f, q1 = 0.f;
#pragma unroll
    for (int s = 0; s < 16; ++s) {
        q0 += QP[((size_t)s * NTOK + v) * DD + tid];
        q1 += QP[((size_t)s * NTOK + v) * DD + 256 + tid];
    }
    q0 += qb[tid];
    q1 += qb[256 + tid];
    float sc[5];
#pragma unroll
    for (int m = 0; m < 5; ++m) {
        if (m < M) {
            const float* K = Kmem + (size_t)m * NTOK * DD + (size_t)v * DD;
            sc[m] = q0 * K[tid] + q1 * K[256 + tid];
        } else sc[m] = 0.f;
    }
#pragma unroll
    for (int m = 0; m < 5; ++m) {
        if (m < M) {
            float x = wave_sum(sc[m]);
            if (lane == 0) s_part[w * 5 + m] = x;
        }
    }
    __syncthreads();
    float cf = conf[v];
    float scf[5];
    float mx = -1e30f;
#pragma unroll
    for (int m = 0; m < 5; ++m) {
        if (m < M) {
            float t = (s_part[m] + s_part[5 + m] + s_part[10 + m] + s_part[15 + m]) * SCALE * cf;
            scf[m] = t;
            mx = fmaxf(mx, t);
        }
    }
    float sum = 0.f;
#pragma unroll
    for (int m = 0; m < 5; ++m) {
        if (m < M) { scf[m] = expf(scf[m] - mx); sum += scf[m]; }
    }
    float inv = 1.0f / sum;
#pragma unroll
    for (int r = 0; r < 4; ++r) {
        int e = r * 256 + tid;
        float ctx = 0.f;
#pragma unroll
        for (int m = 0; m < 5; ++m)
            if (m < M) ctx += scf[m] * Vmem[(size_t)m * NTOK * D2 + (size_t)v * D2 + e];
        z[(size_t)v * D2 + e] += 0.1f * ctx * inv;
    }
}

// ---------------- device finish (token t0, 256 threads, 16 symP partials) ----------------
__device__ __forceinline__ void d_finish(float* __restrict__ z,
                                         const float* __restrict__ sym,
                                         const float* __restrict__ snorm,
                                         const float* __restrict__ con,
                                         const float* __restrict__ conT,
                                         const float* __restrict__ symP,
                                         float* __restrict__ conf,
                                         float* __restrict__ symErr,
                                         float* __restrict__ conErr,
                                         int t0, float* __restrict__ sm) {
    int tid = threadIdx.x;
    int lane = tid & 63, w = tid >> 6;
    float* s_z  = sm;
    float* s_pd = sm + 1024;
    float* s_pc = sm + 1280;
    float* wred = sm + 1536;          // 16 slots
    int*  wredi = (int*)(sm + 1552);  // 4 slots
    int*  s_ci  = (int*)(sm + 1568);

    ((float4*)s_z)[tid] = ((const float4*)(z + (size_t)t0 * D2))[tid];
    __syncthreads();

    // ||z||^2
    {
        float a0 = s_z[tid], a1 = s_z[tid + 256], a2 = s_z[tid + 512], a3 = s_z[tid + 768];
        float nrm = wave_sum(a0*a0 + a1*a1 + a2*a2 + a3*a3);
        if (lane == 0) wred[w] = nrm;
    }
    __syncthreads();
    float znorm = wred[0] + wred[1] + wred[2] + wred[3];

    // sym argmin: 2 codes per thread
    float dbest = 1e30f; int ibest = 0;
#pragma unroll
    for (int cc = 0; cc < 2; ++cc) {
        int c = cc * 256 + tid;
        float dot = 0.f;
#pragma unroll
        for (int s = 0; s < 16; ++s)
            dot += symP[((size_t)s * NTOK + t0) * NSYM + c];
        float d = (znorm + snorm[c]) - 2.f * dot;
        if (d < dbest || (d == dbest && c < ibest)) { dbest = d; ibest = c; }
    }
    wave_argmin(dbest, ibest);
    if (lane == 0) { wred[4 + w] = dbest; wredi[w] = ibest; }
    __syncthreads();
    float dmin = wred[4]; int si = wredi[0];
#pragma unroll
    for (int k = 1; k < 4; ++k) {
        float o = wred[4 + k]; int oi = wredi[k];
        if (o < dmin || (o == dmin && oi < si)) { dmin = o; si = oi; }
    }
    if (tid == 0) conf[t0] = 1.0f / (1.0f + dmin);

    // straight-through update + symErr + ||zs||^2
    {
        const float* crow = sym + (size_t)si * D2;
        float errp = 0.f, zn2 = 0.f;
#pragma unroll
        for (int r = 0; r < 4; ++r) {
            int e = r * 256 + tid;
            float zf = s_z[e];
            float diff = crow[e] - zf;
            errp += diff * diff;
            float zn = zf + diff;
            zn2 += zn * zn;
            s_z[e] = zn;
            z[(size_t)t0 * D2 + e] = zn;
        }
        errp = wave_sum(errp);
        zn2  = wave_sum(zn2);
        if (lane == 0) { wred[8 + w] = errp; wred[12 + w] = zn2; }
    }
    __syncthreads();
    if (tid == 0) symErr[t0] += wred[8] + wred[9] + wred[10] + wred[11];
    float zsnorm = wred[12] + wred[13] + wred[14] + wred[15];

    // con partial dots: 4 k-slices of 256
    {
        int c = tid & 63, sl = tid >> 6;
        float pd = 0.f, pc = 0.f;
        int kk0 = sl * 256;
#pragma unroll 4
        for (int k = kk0; k < kk0 + 256; ++k) {
            float wv = conT[(size_t)k * NCON + c];
            pd += wv * s_z[k];
            pc += wv * wv;
        }
        s_pd[tid] = pd; s_pc[tid] = pc;
    }
    __syncthreads();
    if (tid < 64) {
        float dot2 = s_pd[tid] + s_pd[tid + 64] + s_pd[tid + 128] + s_pd[tid + 192];
        float cn2  = s_pc[tid] + s_pc[tid + 64] + s_pc[tid + 128] + s_pc[tid + 192];
        float dc = (zsnorm + cn2) - 2.f * dot2;
        int ic = tid;
        wave_argmin(dc, ic);
        if (tid == 0) s_ci[0] = ic;
    }
    __syncthreads();
    int ci0 = s_ci[0];

    // conErr
    {
        const float* crow = con + (size_t)ci0 * D2;
        float p = 0.f;
#pragma unroll
        for (int r = 0; r < 4; ++r) {
            int e = r * 256 + tid;
            float diff = crow[e] - s_z[e];
            p += diff * diff;
        }
        p = wave_sum(p);
        if (lane == 0) wred[w] = p;
    }
    __syncthreads();
    if (tid == 0) conErr[t0] += wred[0] + wred[1] + wred[2] + wred[3];
}

// ---------------- persistent kernel (regular launch; co-residency by capacity) ----------------
__global__ __launch_bounds__(256, 2) void persist_kernel(
    const int* __restrict__ x,
    const float* __restrict__ qb, const float* __restrict__ kb, const float* __restrict__ vb,
    const float* __restrict__ dec_b, const float* __restrict__ sym, const float* __restrict__ con,
    const float* __restrict__ CW, const float* __restrict__ qwT, const float* __restrict__ KVT,
    const float* __restrict__ symT, const float* __restrict__ decT, const float* __restrict__ conT,
    float* bufA, float* bufB, float* Kmem, float* Vmem, float* rows,
    float* bigP, float* kvP,
    const float* __restrict__ snorm, float* conf, float* symErr, float* conErr,
    const int* __restrict__ hist, float* out, unsigned* bar)
{
    __shared__ __align__(16) float sm[8704];   // 34816 B, unioned across phases
    int blk = blockIdx.x;
    int tid = threadIdx.x;
    float* cur = bufA;
    float* oth = bufB;

    // ================= d = 0 =================
    { // P1: cell split8 (512 blocks)
        int tile = blk >> 3, s = blk & 7;
        int jx = tile & 15, tx = tile >> 4;
        d_gemm(CW, cur, bigP, D2, jx * 64, tx * 64, s * 128, 4, s, sm);
    }
    gsync(bar);
    if (blk < 256) d_epi(bigP, oth, 8, blk);      // P2
    gsync(bar);
    { float* t = cur; cur = oth; oth = t; }
    { // P5: sym gemm split16
        int tile = blk >> 4, s = blk & 15;
        int jx = tile & 7, tx = tile >> 3;
        d_gemm(symT, cur, bigP, NSYM, jx * 64, tx * 64, s * 64, 2, s, sm);
    }
    gsync(bar);
    if (blk < 256) d_finish(cur, sym, snorm, con, conT, bigP, conf, symErr, conErr, blk, sm);
    gsync(bar);

    // ================= d = 1..5 =================
    for (int d = 1; d < NDEPTH; ++d) {
        // P1: cell split2 (blocks 0..127) + KV split4 for slot d-1 (blocks 128..511)
        if (blk < 128) {
            int tile = blk >> 1, s = blk & 1;
            int jx = tile & 15, tx = tile >> 4;
            d_gemm(CW, cur, bigP, D2, jx * 64, tx * 64, s * 512, 16, s, sm);
        } else {
            int q = blk - 128;
            int tile = q >> 2, s = q & 3;
            int jx = tile % 24, tx = tile / 24;
            d_gemm(KVT, cur, kvP, 1536, jx * 64, tx * 64, s * 256, 8, s, sm);
        }
        gsync(bar);
        // P2: epi (ns=2) + kvcomb slot d-1
        if (blk < 256) {
            d_epi(bigP, oth, 2, blk);
        } else {
            int t = blk - 256;
            float* Kslot = Kmem + (size_t)(d - 1) * NTOK * DD;
            float* Vslot = Vmem + (size_t)(d - 1) * NTOK * D2;
#pragma unroll
            for (int r = 0; r < 6; ++r) {
                int e = r * 256 + tid;
                float vv = 0.f;
#pragma unroll
                for (int s = 0; s < 4; ++s)
                    vv += kvP[((size_t)s * NTOK + t) * 1536 + e];
                if (e < DD) Kslot[(size_t)t * DD + e]        = vv + kb[e];
                else        Vslot[(size_t)t * D2 + (e - DD)] = vv + vb[e - DD];
            }
        }
        gsync(bar);
        { float* t = cur; cur = oth; oth = t; }
        { // P3: Q gemm split16
            int tile = blk >> 4, s = blk & 15;
            int jx = tile & 7, tx = tile >> 3;
            d_gemm(qwT, cur, bigP, DD, jx * 64, tx * 64, s * 64, 2, s, sm);
        }
        gsync(bar);
        if (blk < 256) d_attend(cur, bigP, qb, Kmem, Vmem, conf, d, blk, sm);  // P4
        gsync(bar);
        { // P5: sym gemm split16
            int tile = blk >> 4, s = blk & 15;
            int jx = tile & 7, tx = tile >> 3;
            d_gemm(symT, cur, bigP, NSYM, jx * 64, tx * 64, s * 64, 2, s, sm);
        }
        gsync(bar);
        if (blk < 256) d_finish(cur, sym, snorm, con, conT, bigP, conf, symErr, conErr, blk, sm); // P6
        gsync(bar);
    }

    // ================= look iterations =================
    for (int l = 0; l < NLOOK; ++l) {
        {
            int tile = blk >> 3, s = blk & 7;
            int jx = tile & 15, tx = tile >> 4;
            d_gemm(CW, cur, bigP, D2, jx * 64, tx * 64, s * 128, 4, s, sm);
        }
        gsync(bar);
        if (blk < 256) d_epi(bigP, oth, 8, blk);
        gsync(bar);
        { float* t = cur; cur = oth; oth = t; }
    }

    // ================= decode =================
    if (blk < 256) {   // dec gemm split16 (16 tiles x 16 splits)
        int tile = blk >> 4, s = blk & 15;
        int jx = tile & 3, tx = tile >> 2;
        d_gemm(decT, cur, bigP, VOCAB, jx * 64, tx * 64, s * 64, 2, s, sm);
    }
    gsync(bar);
    if (blk < 256) {   // deccomb
        float v = 0.f;
#pragma unroll
        for (int s = 0; s < 16; ++s)
            v += bigP[((size_t)s * NTOK + blk) * VOCAB + tid];
        rows[(size_t)blk * VOCAB + tid] = v + dec_b[tid];
    }
    gsync(bar);
    // scatter: 32 positions per block (512 * 32 = 16384)
#pragma unroll
    for (int r = 0; r < 8; ++r) {
        int pos = blk * 32 + r * 4 + (tid >> 6);
        int lane = tid & 63;
        int v = x[pos];
        ((float4*)(out + (size_t)pos * VOCAB))[lane] =
            ((const float4*)(rows + (size_t)v * VOCAB))[lane];
    }
    // loss (block 0)
    if (blk == 0) {
        __syncthreads();
        double* rs = (double*)sm;
        double* rc = rs + 256;
        rs[tid] = (double)hist[tid] * (double)symErr[tid];
        rc[tid] = (double)hist[tid] * (double)conErr[tid];
        __syncthreads();
        for (int off = 128; off > 0; off >>= 1) {
            if (tid < off) { rs[tid] += rs[tid + off]; rc[tid] += rc[tid + off]; }
            __syncthreads();
        }
        if (tid == 0) {
            const double denom = (double)BS_TOT * (double)D2;
            out[(size_t)BS_TOT * VOCAB]     = (float)(1.25 * rs[0] / denom);
            out[(size_t)BS_TOT * VOCAB + 1] = (float)(1.25 * rc[0] / denom);
        }
    }
}

// ---------------- batched setup: 6 transposes + zero-init (incl. barrier state) ----------------
__global__ void tbatch_kernel(const float* __restrict__ qw, const float* __restrict__ kw,
                              const float* __restrict__ vw, const float* __restrict__ sym,
                              const float* __restrict__ dec_w, const float* __restrict__ con,
                              float* __restrict__ qwT, float* __restrict__ KVT,
                              float* __restrict__ symT, float* __restrict__ decT,
                              float* __restrict__ conT,
                              float* __restrict__ symErr, float* __restrict__ conErr,
                              int* __restrict__ hist, unsigned* __restrict__ bar) {
    int b = blockIdx.x;
    const float* in; float* out; int ldo;
    if      (b < 512)  {           in = qw;    out = qwT;      ldo = DD;    }
    else if (b < 1024) { b -= 512; in = kw;    out = KVT;      ldo = 1536;  }
    else if (b < 2048) { b -= 1024; in = vw;   out = KVT + DD; ldo = 1536;  }
    else if (b < 2560) { b -= 2048; in = sym;  out = symT;     ldo = NSYM;  }
    else if (b < 2816) { b -= 2560; in = dec_w; out = decT;    ldo = VOCAB; }
    else if (b < 2880) { b -= 2816; in = con;  out = conT;     ldo = NCON;  }
    else {
        int t = threadIdx.y * 32 + threadIdx.x;  // 256 threads
        symErr[t] = 0.f; conErr[t] = 0.f; hist[t] = 0;
        bar[t] = 0u; bar[256 + t] = 0u;
        return;
    }
    __shared__ float t[32][33];
    int bx = b & 31, by = b >> 5;
    int c0 = bx * 32, r0 = by * 32;
    int x = threadIdx.x, y = threadIdx.y;
#pragma unroll
    for (int i = 0; i < 32; i += 8)
        t[y + i][x] = in[(size_t)(r0 + y + i) * D2 + c0 + x];
    __syncthreads();
#pragma unroll
    for (int i = 0; i < 32; i += 8)
        out[(size_t)(c0 + y + i) * ldo + r0 + x] = t[x][y + i];
}

__global__ void hist_kernel(const int* __restrict__ x, int* __restrict__ hist) {
    int i = blockIdx.x * 256 + threadIdx.x;
    atomicAdd(&hist[x[i]], 1);
}

// ---------------- build combined cell weight CW[1024][1024] ----------------
__global__ void buildcw_kernel(const float* __restrict__ Wr, const float* __restrict__ Wi,
                               float* __restrict__ CW) {
    __shared__ float tr[32][33], ti[32][33];
    int j0 = blockIdx.x * 32, k0 = blockIdx.y * 32;
    int x = threadIdx.x, y = threadIdx.y;
#pragma unroll
    for (int i = 0; i < 32; i += 8) {
        tr[y + i][x] = Wr[(size_t)(j0 + y + i) * DD + k0 + x];
        ti[y + i][x] = Wi[(size_t)(j0 + y + i) * DD + k0 + x];
    }
    __syncthreads();
#pragma unroll
    for (int i = 0; i < 32; i += 8) {
        float vr = tr[x][y + i];
        float vi = ti[x][y + i];
        int k = k0 + y + i, j = j0 + x;
        CW[(size_t)k * D2 + j]                    = vr;
        CW[(size_t)k * D2 + DD + j]               = vi;
        CW[(size_t)(DD + k) * D2 + j]             = -vi;
        CW[(size_t)(DD + k) * D2 + DD + j]        = vr;
    }
}

// ---------------- embed (blocks 0..255) + sym norms (blocks 256..767), block 512 ----------------
__global__ __launch_bounds__(512) void symembed_kernel(const float* __restrict__ mag,
                                                       const float* __restrict__ phase,
                                                       const float* __restrict__ sym,
                                                       float* __restrict__ dst,
                                                       float* __restrict__ snorm) {
    int bid = blockIdx.x, tid = threadIdx.x;
    if (bid < NTOK) {
        int v = bid, j = tid;
        float r = mag[v * DD + j], t = phase[v * DD + j];
        dst[(size_t)v * D2 + j]      = r * cosf(t);
        dst[(size_t)v * D2 + DD + j] = r * sinf(t);
        return;
    }
    int c = bid - NTOK;
    float2 vv = ((const float2*)(sym + (size_t)c * D2))[tid];
    float p = vv.x * vv.x + vv.y * vv.y;
    p = wave_sum(p);
    __shared__ float s_w[8];
    int lane = tid & 63, w = tid >> 6;
    if (lane == 0) s_w[w] = p;
    __syncthreads();
    if (tid == 0) {
        float s = 0.f;
#pragma unroll
        for (int k = 0; k < 8; ++k) s += s_w[k];
        snorm[c] = s;
    }
}

// ---------------- host ----------------
extern "C" void kernel_launch(void* const* d_in, const int* in_sizes, int n_in,
                              void* d_out, int out_size, void* d_ws, size_t ws_size,
                              hipStream_t stream) {
    const int*   x     = (const int*)  d_in[0];
    const float* mag   = (const float*)d_in[1];
    const float* phase = (const float*)d_in[2];
    const float* Wr    = (const float*)d_in[3];
    const float* Wi    = (const float*)d_in[4];
    const float* qw    = (const float*)d_in[5];
    const float* qb    = (const float*)d_in[6];
    const float* kw    = (const float*)d_in[7];
    const float* kb    = (const float*)d_in[8];
    const float* vw    = (const float*)d_in[9];
    const float* vb    = (const float*)d_in[10];
    const float* dec_w = (const float*)d_in[11];
    const float* dec_b = (const float*)d_in[12];
    const float* sym   = (const float*)d_in[13];
    const float* con   = (const float*)d_in[14];
    float* out = (float*)d_out;

    // workspace layout (floats); total ~42.5 MB
    float* ws     = (float*)d_ws;
    float* bufA   = ws;                          // 256*1024
    float* bufB   = bufA + NTOK * D2;            // 256*1024
    float* Kmem   = bufB + NTOK * D2;            // 6*256*512
    float* Vmem   = Kmem + NDEPTH * NTOK * DD;   // 6*256*1024
    float* rows   = Vmem + NDEPTH * NTOK * D2;   // 256*256
    float* CW     = rows + NTOK * VOCAB;         // 1024*1024
    float* qwT    = CW + D2 * D2;                // 1024*512
    float* KVT    = qwT + D2 * DD;               // 1024*1536
    float* symT   = KVT + D2 * 1536;             // 1024*512
    float* decT   = symT + D2 * NSYM;            // 1024*256
    float* conT   = decT + D2 * VOCAB;           // 1024*64
    float* bigP   = conT + D2 * NCON;            // 2,097,152
    float* kvP    = bigP + 8 * NTOK * D2;        // 4*256*1536
    float* snorm  = kvP + 4 * NTOK * 1536;       // 512
    float* conf   = snorm + NSYM;                // 256
    float* symErr = conf + NTOK;                 // 256
    float* conErr = symErr + NTOK;               // 256
    int*   hist   = (int*)(conErr + NTOK);       // 256
    unsigned* bar = (unsigned*)(hist + NTOK);    // 512

    dim3 tb(32, 8);
    tbatch_kernel<<<2881, tb, 0, stream>>>(qw, kw, vw, sym, dec_w, con,
                                           qwT, KVT, symT, decT, conT,
                                           symErr, conErr, hist, bar);
    buildcw_kernel<<<dim3(16, 16), tb, 0, stream>>>(Wr, Wi, CW);
    hist_kernel<<<BS_TOT / 256, 256, 0, stream>>>(x, hist);
    symembed_kernel<<<NTOK + NSYM, 512, 0, stream>>>(mag, phase, sym, bufA, snorm);

    persist_kernel<<<512, 256, 0, stream>>>(
        x, qb, kb, vb, dec_b, sym, con,
        CW, qwT, KVT, symT, decT, conT,
        bufA, bufB, Kmem, Vmem, rows, bigP, kvP,
        snorm, conf, symErr, conErr, hist, out, bar);
}

// Round 6
// 709.765 us; speedup vs baseline: 6.9229x; 6.9229x over previous
//
#include <hip/hip_runtime.h>
#include <math.h>

// Problem constants
constexpr int DD    = 512;     // D
constexpr int D2    = 1024;    // 2D
constexpr int NTOK  = 256;     // vocab V (unique tokens = unique pipelines)
constexpr int NSYM  = 512;
constexpr int NCON  = 64;
constexpr int VOCAB = 256;
constexpr int BS_TOT = 32 * 512;   // B*S = 16384
constexpr int NDEPTH = 6;
constexpr int NLOOK  = 3;
constexpr float EPSF = 1e-8f;
constexpr float SCALE = 0.044194173824159216f; // 512^-0.5

__device__ inline void fma4(float4& a, const float4& w, float s) {
    a.x += w.x * s; a.y += w.y * s; a.z += w.z * s; a.w += w.w * s;
}

__device__ inline float wave_sum(float x) {
#pragma unroll
    for (int off = 32; off; off >>= 1) x += __shfl_xor(x, off, 64);
    return x;
}

__device__ inline void wave_argmin(float& d, int& i) {
#pragma unroll
    for (int off = 32; off; off >>= 1) {
        float od = __shfl_xor(d, off, 64);
        int   oi = __shfl_xor(i, off, 64);
        if (od < d || (od == d && oi < i)) { d = od; i = oi; }
    }
}

// ================= GEMM core: 128t x 64j tile, 8x4 per thread =================
// X: [256][1024] t-major. WT: [1024][N] k-major. P[slot][256][N].
// LDS: sX[32][132] (transposed [k][t]), sW[32][68]. Single buffer + reg prefetch.
// Per k: 3x ds_read_b128, 32 FMA -> VALU-bound (1.33 FLOP/LDS-byte).
__device__ __forceinline__ void d_gemm128(const float* __restrict__ WT,
                                          const float* __restrict__ X,
                                          float* __restrict__ P, int N,
                                          int j0, int t0, int k0, int NC, int slot,
                                          float* __restrict__ sX, float* __restrict__ sW) {
    constexpr int LDX = 132, LDW = 68;
    int tid = threadIdx.x;
    int jq = tid & 15, tq = tid >> 4;

    int tS[4], kqS[4];
#pragma unroll
    for (int i = 0; i < 4; ++i) { int f = tid * 4 + i; tS[i] = f >> 3; kqS[i] = f & 7; }
    int kwS[2], jS[2];
#pragma unroll
    for (int i = 0; i < 2; ++i) { int f = tid * 2 + i; kwS[i] = f >> 4; jS[i] = f & 15; }

    float4 vx[4], vw[2];
    float4 acc[8];
#pragma unroll
    for (int r = 0; r < 8; ++r) acc[r] = make_float4(0.f, 0.f, 0.f, 0.f);

#define GL128(kb) do { \
        vx[0] = *(const float4*)&X[(size_t)(t0 + tS[0]) * D2 + (kb) + kqS[0] * 4]; \
        vx[1] = *(const float4*)&X[(size_t)(t0 + tS[1]) * D2 + (kb) + kqS[1] * 4]; \
        vx[2] = *(const float4*)&X[(size_t)(t0 + tS[2]) * D2 + (kb) + kqS[2] * 4]; \
        vx[3] = *(const float4*)&X[(size_t)(t0 + tS[3]) * D2 + (kb) + kqS[3] * 4]; \
        vw[0] = *(const float4*)&WT[(size_t)((kb) + kwS[0]) * N + j0 + jS[0] * 4]; \
        vw[1] = *(const float4*)&WT[(size_t)((kb) + kwS[1]) * N + j0 + jS[1] * 4]; \
    } while (0)
#define LS128() do { \
        _Pragma("unroll") \
        for (int i = 0; i < 4; ++i) { \
            sX[(kqS[i] * 4 + 0) * LDX + tS[i]] = vx[i].x; \
            sX[(kqS[i] * 4 + 1) * LDX + tS[i]] = vx[i].y; \
            sX[(kqS[i] * 4 + 2) * LDX + tS[i]] = vx[i].z; \
            sX[(kqS[i] * 4 + 3) * LDX + tS[i]] = vx[i].w; \
        } \
        *(float4*)&sW[kwS[0] * LDW + jS[0] * 4] = vw[0]; \
        *(float4*)&sW[kwS[1] * LDW + jS[1] * 4] = vw[1]; \
    } while (0)

    GL128(k0);
    LS128();
    __syncthreads();

    for (int kc = 0; kc < NC; ++kc) {
        if (kc + 1 < NC) GL128(k0 + (kc + 1) * 32);
#pragma unroll 4
        for (int k = 0; k < 32; ++k) {
            float4 a0 = *(const float4*)&sX[k * LDX + tq * 8];
            float4 a1 = *(const float4*)&sX[k * LDX + tq * 8 + 4];
            float4 bb = *(const float4*)&sW[k * LDW + jq * 4];
            fma4(acc[0], bb, a0.x); fma4(acc[1], bb, a0.y);
            fma4(acc[2], bb, a0.z); fma4(acc[3], bb, a0.w);
            fma4(acc[4], bb, a1.x); fma4(acc[5], bb, a1.y);
            fma4(acc[6], bb, a1.z); fma4(acc[7], bb, a1.w);
        }
        if (kc + 1 < NC) {
            __syncthreads();
            LS128();
            __syncthreads();
        }
    }
#undef GL128
#undef LS128

#pragma unroll
    for (int r = 0; r < 8; ++r) {
        size_t o = ((size_t)slot * NTOK + (t0 + tq * 8 + r)) * N + j0 + jq * 4;
        *(float4*)&P[o] = acc[r];
    }
}

// generic GEMM launch: grid (ntj, 2, S); K-slice = NC*32 per z
__global__ __launch_bounds__(256, 2) void gemm128_kernel(const float* __restrict__ WT,
                                                         const float* __restrict__ X,
                                                         float* __restrict__ P,
                                                         int N, int NC) {
    __shared__ __align__(16) float sX[32 * 132];
    __shared__ __align__(16) float sW[32 * 68];
    int j0 = blockIdx.x * 64;
    int t0 = blockIdx.y * 128;
    int s  = blockIdx.z;
    d_gemm128(WT, X, P, N, j0, t0, s * NC * 32, NC, s, sX, sW);
}

// merged cell + KV gemm: grid 448 flat. blocks [0,256): cell (S=8,NC=4);
// blocks [256,448): KV (S=4,NC=8, N=1536)
__global__ __launch_bounds__(256, 2) void cellkv_kernel(const float* __restrict__ CW,
                                                        const float* __restrict__ KVT,
                                                        const float* __restrict__ X,
                                                        float* __restrict__ cellP,
                                                        float* __restrict__ kvP) {
    __shared__ __align__(16) float sX[32 * 132];
    __shared__ __align__(16) float sW[32 * 68];
    int b = blockIdx.x;
    if (b < 256) {
        int s = b & 7, tile = b >> 3;
        int jx = tile & 15, tx = tile >> 4;
        d_gemm128(CW, X, cellP, D2, jx * 64, tx * 128, s * 128, 4, s, sX, sW);
    } else {
        int q = b - 256;
        int s = q & 3, tile = q >> 2;          // tile in [0,48)
        int jx = tile % 24, tx = tile / 24;
        d_gemm128(KVT, X, kvP, 1536, jx * 64, tx * 128, s * 256, 8, s, sX, sW);
    }
}

// ---------------- merged cell epilogue (bx<2) + prev-iter KV combine (bx>=2) ----------------
// grid (8, 256) with doKV=1, or (2,256) with doKV=0. block 256.
__global__ __launch_bounds__(256) void epikv_kernel(const float* __restrict__ cellP,
                                                    float* __restrict__ z,
                                                    const float* __restrict__ kvP,
                                                    const float* __restrict__ kb,
                                                    const float* __restrict__ vb,
                                                    float* __restrict__ Kslot,
                                                    float* __restrict__ Vslot,
                                                    int doKV) {
    int bx = blockIdx.x, t = blockIdx.y, tid = threadIdx.x;
    if (bx < 2) {
        int j = bx * 256 + tid;
        float lr = 0.f, li = 0.f;
#pragma unroll
        for (int s = 0; s < 8; ++s) {
            lr += cellP[((size_t)s * NTOK + t) * D2 + j];
            li += cellP[((size_t)s * NTOK + t) * D2 + DD + j];
        }
        float m = sqrtf(lr * lr + li * li + EPSF);
        float inv = 1.0f / (1.0f + m);
        z[(size_t)t * D2 + j]      = tanhf(lr * inv);
        z[(size_t)t * D2 + DD + j] = tanhf(li * inv);
    } else if (doKV) {
        int e = (bx - 2) * 256 + tid;
        float v = 0.f;
#pragma unroll
        for (int s = 0; s < 4; ++s)
            v += kvP[((size_t)s * NTOK + t) * 1536 + e];
        if (e < DD) Kslot[(size_t)t * DD + e]        = v + kb[e];
        else        Vslot[(size_t)t * D2 + (e - DD)] = v + vb[e - DD];
    }
}

// ---------------- attend: 16 QP partials, wave-shuffle, grid 256 x 256thr ----------------
__global__ __launch_bounds__(256) void attend16_kernel(float* __restrict__ z,
                                                       const float* __restrict__ QP,
                                                       const float* __restrict__ qb,
                                                       const float* __restrict__ Kmem,
                                                       const float* __restrict__ Vmem,
                                                       const float* __restrict__ conf,
                                                       int M) {
    int v = blockIdx.x, tid = threadIdx.x;
    int lane = tid & 63, w = tid >> 6;
    __shared__ float s_part[4][5];
    float q0 = 0.f, q1 = 0.f;
#pragma unroll
    for (int s = 0; s < 16; ++s) {
        q0 += QP[((size_t)s * NTOK + v) * DD + tid];
        q1 += QP[((size_t)s * NTOK + v) * DD + 256 + tid];
    }
    q0 += qb[tid];
    q1 += qb[256 + tid];
    float sc[5];
#pragma unroll
    for (int m = 0; m < 5; ++m) {
        if (m < M) {
            const float* K = Kmem + (size_t)m * NTOK * DD + (size_t)v * DD;
            sc[m] = q0 * K[tid] + q1 * K[256 + tid];
        } else sc[m] = 0.f;
    }
#pragma unroll
    for (int m = 0; m < 5; ++m) {
        if (m < M) {
            float x = wave_sum(sc[m]);
            if (lane == 0) s_part[w][m] = x;
        }
    }
    __syncthreads();
    float cf = conf[v];
    float scf[5];
    float mx = -1e30f;
#pragma unroll
    for (int m = 0; m < 5; ++m) {
        if (m < M) {
            float t = (s_part[0][m] + s_part[1][m] + s_part[2][m] + s_part[3][m]) * SCALE * cf;
            scf[m] = t;
            mx = fmaxf(mx, t);
        }
    }
    float sum = 0.f;
#pragma unroll
    for (int m = 0; m < 5; ++m) {
        if (m < M) { scf[m] = expf(scf[m] - mx); sum += scf[m]; }
    }
    float inv = 1.0f / sum;
#pragma unroll
    for (int r = 0; r < 4; ++r) {
        int e = r * 256 + tid;
        float ctx = 0.f;
#pragma unroll
        for (int m = 0; m < 5; ++m)
            if (m < M) ctx += scf[m] * Vmem[(size_t)m * NTOK * D2 + (size_t)v * D2 + e];
        z[(size_t)v * D2 + e] += 0.1f * ctx * inv;
    }
}

// ---------------- finish: 16 symP partials, 256 threads ----------------
__global__ __launch_bounds__(256) void finish16_kernel(float* __restrict__ z,
                                                       const float* __restrict__ sym,
                                                       const float* __restrict__ snorm,
                                                       const float* __restrict__ con,
                                                       const float* __restrict__ conT,
                                                       const float* __restrict__ symP,
                                                       float* __restrict__ conf,
                                                       float* __restrict__ symErr,
                                                       float* __restrict__ conErr) {
    int t0 = blockIdx.x, tid = threadIdx.x;
    int lane = tid & 63, w = tid >> 6;
    __shared__ __align__(16) float s_z[D2];
    __shared__ float s_pd[256], s_pc[256];
    __shared__ float wred[16];
    __shared__ int   wredi[4];
    __shared__ int   s_ci[1];

    ((float4*)s_z)[tid] = ((const float4*)(z + (size_t)t0 * D2))[tid];
    __syncthreads();

    // ||z||^2
    {
        float a0 = s_z[tid], a1 = s_z[tid + 256], a2 = s_z[tid + 512], a3 = s_z[tid + 768];
        float nrm = wave_sum(a0*a0 + a1*a1 + a2*a2 + a3*a3);
        if (lane == 0) wred[w] = nrm;
    }
    __syncthreads();
    float znorm = wred[0] + wred[1] + wred[2] + wred[3];

    // sym argmin: 2 codes per thread
    float dbest = 1e30f; int ibest = 0;
#pragma unroll
    for (int cc = 0; cc < 2; ++cc) {
        int c = cc * 256 + tid;
        float dot = 0.f;
#pragma unroll
        for (int s = 0; s < 16; ++s)
            dot += symP[((size_t)s * NTOK + t0) * NSYM + c];
        float d = (znorm + snorm[c]) - 2.f * dot;
        if (d < dbest || (d == dbest && c < ibest)) { dbest = d; ibest = c; }
    }
    wave_argmin(dbest, ibest);
    if (lane == 0) { wred[4 + w] = dbest; wredi[w] = ibest; }
    __syncthreads();
    float dmin = wred[4]; int si = wredi[0];
#pragma unroll
    for (int k = 1; k < 4; ++k) {
        float o = wred[4 + k]; int oi = wredi[k];
        if (o < dmin || (o == dmin && oi < si)) { dmin = o; si = oi; }
    }
    if (tid == 0) conf[t0] = 1.0f / (1.0f + dmin);

    // straight-through update + symErr + ||zs||^2
    {
        const float* crow = sym + (size_t)si * D2;
        float errp = 0.f, zn2 = 0.f;
#pragma unroll
        for (int r = 0; r < 4; ++r) {
            int e = r * 256 + tid;
            float zf = s_z[e];
            float diff = crow[e] - zf;
            errp += diff * diff;
            float zn = zf + diff;
            zn2 += zn * zn;
            s_z[e] = zn;
            z[(size_t)t0 * D2 + e] = zn;
        }
        errp = wave_sum(errp);
        zn2  = wave_sum(zn2);
        if (lane == 0) { wred[8 + w] = errp; wred[12 + w] = zn2; }
    }
    __syncthreads();
    if (tid == 0) symErr[t0] += wred[8] + wred[9] + wred[10] + wred[11];
    float zsnorm = wred[12] + wred[13] + wred[14] + wred[15];

    // con partial dots: 4 k-slices of 256
    {
        int c = tid & 63, sl = tid >> 6;
        float pd = 0.f, pc = 0.f;
        int kk0 = sl * 256;
#pragma unroll 4
        for (int k = kk0; k < kk0 + 256; ++k) {
            float wv = conT[(size_t)k * NCON + c];
            pd += wv * s_z[k];
            pc += wv * wv;
        }
        s_pd[tid] = pd; s_pc[tid] = pc;
    }
    __syncthreads();
    if (tid < 64) {
        float dot2 = s_pd[tid] + s_pd[tid + 64] + s_pd[tid + 128] + s_pd[tid + 192];
        float cn2  = s_pc[tid] + s_pc[tid + 64] + s_pc[tid + 128] + s_pc[tid + 192];
        float dc = (zsnorm + cn2) - 2.f * dot2;
        int ic = tid;
        wave_argmin(dc, ic);
        if (tid == 0) s_ci[0] = ic;
    }
    __syncthreads();
    int ci0 = s_ci[0];

    // conErr
    {
        const float* crow = con + (size_t)ci0 * D2;
        float p = 0.f;
#pragma unroll
        for (int r = 0; r < 4; ++r) {
            int e = r * 256 + tid;
            float diff = crow[e] - s_z[e];
            p += diff * diff;
        }
        p = wave_sum(p);
        if (lane == 0) wred[w] = p;
    }
    __syncthreads();
    if (tid == 0) conErr[t0] += wred[0] + wred[1] + wred[2] + wred[3];
}

// ---------------- dec combine: rows = sum of 16 partials + dec_b ----------------
__global__ void deccomb_kernel(const float* __restrict__ P, const float* __restrict__ db,
                               float* __restrict__ rows) {
    int t = blockIdx.x, j = threadIdx.x;
    float v = 0.f;
#pragma unroll
    for (int s = 0; s < 16; ++s)
        v += P[((size_t)s * NTOK + t) * VOCAB + j];
    rows[(size_t)t * VOCAB + j] = v + db[j];
}

// ---------------- scatter + fused loss (last block) ----------------
__global__ __launch_bounds__(256) void scatter_kernel(const int* __restrict__ x,
                                                      const float* __restrict__ rows,
                                                      float* __restrict__ out,
                                                      const int* __restrict__ hist,
                                                      const float* __restrict__ symErr,
                                                      const float* __restrict__ conErr) {
    int tid = threadIdx.x;
    if (blockIdx.x == BS_TOT / 4) {
        __shared__ double rs[256], rc[256];
        rs[tid] = (double)hist[tid] * (double)symErr[tid];
        rc[tid] = (double)hist[tid] * (double)conErr[tid];
        __syncthreads();
        for (int off = 128; off > 0; off >>= 1) {
            if (tid < off) { rs[tid] += rs[tid + off]; rc[tid] += rc[tid + off]; }
            __syncthreads();
        }
        if (tid == 0) {
            const double denom = (double)BS_TOT * (double)D2;
            out[(size_t)BS_TOT * VOCAB]     = (float)(1.25 * rs[0] / denom);
            out[(size_t)BS_TOT * VOCAB + 1] = (float)(1.25 * rc[0] / denom);
        }
        return;
    }
    int pos = blockIdx.x * 4 + (tid >> 6);
    int lane = tid & 63;
    int v = x[pos];
    const float4* r = (const float4*)(rows + (size_t)v * VOCAB);
    ((float4*)(out + (size_t)pos * VOCAB))[lane] = r[lane];
}

// ---------------- batched setup: 6 transposes + zero-init ----------------
__global__ void tbatch_kernel(const float* __restrict__ qw, const float* __restrict__ kw,
                              const float* __restrict__ vw, const float* __restrict__ sym,
                              const float* __restrict__ dec_w, const float* __restrict__ con,
                              float* __restrict__ qwT, float* __restrict__ KVT,
                              float* __restrict__ symT, float* __restrict__ decT,
                              float* __restrict__ conT,
                              float* __restrict__ symErr, float* __restrict__ conErr,
                              int* __restrict__ hist) {
    int b = blockIdx.x;
    const float* in; float* out; int ldo;
    if      (b < 512)  {           in = qw;    out = qwT;      ldo = DD;    }
    else if (b < 1024) { b -= 512; in = kw;    out = KVT;      ldo = 1536;  }
    else if (b < 2048) { b -= 1024; in = vw;   out = KVT + DD; ldo = 1536;  }
    else if (b < 2560) { b -= 2048; in = sym;  out = symT;     ldo = NSYM;  }
    else if (b < 2816) { b -= 2560; in = dec_w; out = decT;    ldo = VOCAB; }
    else if (b < 2880) { b -= 2816; in = con;  out = conT;     ldo = NCON;  }
    else {
        int t = threadIdx.y * 32 + threadIdx.x;  // 256 threads
        symErr[t] = 0.f; conErr[t] = 0.f; hist[t] = 0;
        return;
    }
    __shared__ float t[32][33];
    int bx = b & 31, by = b >> 5;
    int c0 = bx * 32, r0 = by * 32;
    int x = threadIdx.x, y = threadIdx.y;
#pragma unroll
    for (int i = 0; i < 32; i += 8)
        t[y + i][x] = in[(size_t)(r0 + y + i) * D2 + c0 + x];
    __syncthreads();
#pragma unroll
    for (int i = 0; i < 32; i += 8)
        out[(size_t)(c0 + y + i) * ldo + r0 + x] = t[x][y + i];
}

__global__ void hist_kernel(const int* __restrict__ x, int* __restrict__ hist) {
    int i = blockIdx.x * 256 + threadIdx.x;
    atomicAdd(&hist[x[i]], 1);
}

// ---------------- build combined cell weight CW[1024][1024] ----------------
__global__ void buildcw_kernel(const float* __restrict__ Wr, const float* __restrict__ Wi,
                               float* __restrict__ CW) {
    __shared__ float tr[32][33], ti[32][33];
    int j0 = blockIdx.x * 32, k0 = blockIdx.y * 32;
    int x = threadIdx.x, y = threadIdx.y;
#pragma unroll
    for (int i = 0; i < 32; i += 8) {
        tr[y + i][x] = Wr[(size_t)(j0 + y + i) * DD + k0 + x];
        ti[y + i][x] = Wi[(size_t)(j0 + y + i) * DD + k0 + x];
    }
    __syncthreads();
#pragma unroll
    for (int i = 0; i < 32; i += 8) {
        float vr = tr[x][y + i];
        float vi = ti[x][y + i];
        int k = k0 + y + i, j = j0 + x;
        CW[(size_t)k * D2 + j]                    = vr;
        CW[(size_t)k * D2 + DD + j]               = vi;
        CW[(size_t)(DD + k) * D2 + j]             = -vi;
        CW[(size_t)(DD + k) * D2 + DD + j]        = vr;
    }
}

// ---------------- embed (blocks 0..255) + sym norms (blocks 256..767), block 512 ----------------
__global__ __launch_bounds__(512) void symembed_kernel(const float* __restrict__ mag,
                                                       const float* __restrict__ phase,
                                                       const float* __restrict__ sym,
                                                       float* __restrict__ dst,
                                                       float* __restrict__ snorm) {
    int bid = blockIdx.x, tid = threadIdx.x;
    if (bid < NTOK) {
        int v = bid, j = tid;
        float r = mag[v * DD + j], t = phase[v * DD + j];
        dst[(size_t)v * D2 + j]      = r * cosf(t);
        dst[(size_t)v * D2 + DD + j] = r * sinf(t);
        return;
    }
    int c = bid - NTOK;
    float2 vv = ((const float2*)(sym + (size_t)c * D2))[tid];
    float p = vv.x * vv.x + vv.y * vv.y;
    p = wave_sum(p);
    __shared__ float s_w[8];
    int lane = tid & 63, w = tid >> 6;
    if (lane == 0) s_w[w] = p;
    __syncthreads();
    if (tid == 0) {
        float s = 0.f;
#pragma unroll
        for (int k = 0; k < 8; ++k) s += s_w[k];
        snorm[c] = s;
    }
}

// ---------------- host ----------------
extern "C" void kernel_launch(void* const* d_in, const int* in_sizes, int n_in,
                              void* d_out, int out_size, void* d_ws, size_t ws_size,
                              hipStream_t stream) {
    const int*   x     = (const int*)  d_in[0];
    const float* mag   = (const float*)d_in[1];
    const float* phase = (const float*)d_in[2];
    const float* Wr    = (const float*)d_in[3];
    const float* Wi    = (const float*)d_in[4];
    const float* qw    = (const float*)d_in[5];
    const float* qb    = (const float*)d_in[6];
    const float* kw    = (const float*)d_in[7];
    const float* kb    = (const float*)d_in[8];
    const float* vw    = (const float*)d_in[9];
    const float* vb    = (const float*)d_in[10];
    const float* dec_w = (const float*)d_in[11];
    const float* dec_b = (const float*)d_in[12];
    const float* sym   = (const float*)d_in[13];
    const float* con   = (const float*)d_in[14];
    float* out = (float*)d_out;

    // workspace layout (floats); total ~42.5 MB
    float* ws     = (float*)d_ws;
    float* bufA   = ws;                          // 256*1024
    float* bufB   = bufA + NTOK * D2;            // 256*1024
    float* Kmem   = bufB + NTOK * D2;            // 6*256*512
    float* Vmem   = Kmem + NDEPTH * NTOK * DD;   // 6*256*1024
    float* rows   = Vmem + NDEPTH * NTOK * D2;   // 256*256
    float* CW     = rows + NTOK * VOCAB;         // 1024*1024
    float* qwT    = CW + D2 * D2;                // 1024*512
    float* KVT    = qwT + D2 * DD;               // 1024*1536
    float* symT   = KVT + D2 * 1536;             // 1024*512
    float* decT   = symT + D2 * NSYM;            // 1024*256
    float* conT   = decT + D2 * VOCAB;           // 1024*64
    float* bigP   = conT + D2 * NCON;            // 2,097,152 floats
    float* kvP    = bigP + 8 * NTOK * D2;        // 4*256*1536
    float* snorm  = kvP + 4 * NTOK * 1536;       // 512
    float* conf   = snorm + NSYM;                // 256
    float* symErr = conf + NTOK;                 // 256
    float* conErr = symErr + NTOK;               // 256
    int*   hist   = (int*)(conErr + NTOK);       // 256

    float* QP   = bigP;                 // 16*256*512 = full bigP
    float* symP = bigP;                 // 16*256*512
    float* decP = bigP;                 // 16*256*256

    dim3 tb(32, 8);
    tbatch_kernel<<<2881, tb, 0, stream>>>(qw, kw, vw, sym, dec_w, con,
                                           qwT, KVT, symT, decT, conT,
                                           symErr, conErr, hist);
    buildcw_kernel<<<dim3(16, 16), tb, 0, stream>>>(Wr, Wi, CW);
    hist_kernel<<<BS_TOT / 256, 256, 0, stream>>>(x, hist);
    symembed_kernel<<<NTOK + NSYM, 512, 0, stream>>>(mag, phase, sym, bufA, snorm);

    float* cur = bufA;
    float* oth = bufB;
    for (int d = 0; d < NDEPTH; ++d) {
        if (d == 0) {
            gemm128_kernel<<<dim3(16, 2, 8), 256, 0, stream>>>(CW, cur, bigP, D2, 4);
            epikv_kernel<<<dim3(2, 256), 256, 0, stream>>>(bigP, oth, kvP, kb, vb,
                                                           Kmem, Vmem, 0);
        } else {
            cellkv_kernel<<<448, 256, 0, stream>>>(CW, KVT, cur, bigP, kvP);
            epikv_kernel<<<dim3(8, 256), 256, 0, stream>>>(
                bigP, oth, kvP, kb, vb,
                Kmem + (size_t)(d - 1) * NTOK * DD,
                Vmem + (size_t)(d - 1) * NTOK * D2, 1);
        }
        { float* t = cur; cur = oth; oth = t; }
        if (d > 0) {
            gemm128_kernel<<<dim3(8, 2, 16), 256, 0, stream>>>(qwT, cur, QP, DD, 2);
            attend16_kernel<<<NTOK, 256, 0, stream>>>(cur, QP, qb, Kmem, Vmem, conf, d);
        }
        gemm128_kernel<<<dim3(8, 2, 16), 256, 0, stream>>>(symT, cur, symP, NSYM, 2);
        finish16_kernel<<<NTOK, 256, 0, stream>>>(cur, sym, snorm, con, conT, symP,
                                                  conf, symErr, conErr);
    }
    for (int l = 0; l < NLOOK; ++l) {
        gemm128_kernel<<<dim3(16, 2, 8), 256, 0, stream>>>(CW, cur, bigP, D2, 4);
        epikv_kernel<<<dim3(2, 256), 256, 0, stream>>>(bigP, oth, kvP, kb, vb,
                                                       Kmem, Vmem, 0);
        { float* t = cur; cur = oth; oth = t; }
    }
    gemm128_kernel<<<dim3(4, 2, 16), 256, 0, stream>>>(decT, cur, decP, VOCAB, 2);
    deccomb_kernel<<<256, 256, 0, stream>>>(decP, dec_b, rows);
    scatter_kernel<<<BS_TOT / 4 + 1, 256, 0, stream>>>(x, rows, out, hist, symErr, conErr);
}

// Round 7
// 583.902 us; speedup vs baseline: 8.4152x; 1.2156x over previous
//
#include <hip/hip_runtime.h>
#include <math.h>

// Problem constants
constexpr int DD    = 512;     // D
constexpr int D2    = 1024;    // 2D
constexpr int NTOK  = 256;     // vocab V (unique tokens = unique pipelines)
constexpr int NSYM  = 512;
constexpr int NCON  = 64;
constexpr int VOCAB = 256;
constexpr int BS_TOT = 32 * 512;   // B*S = 16384
constexpr int NDEPTH = 6;
constexpr int NLOOK  = 3;
constexpr float EPSF = 1e-8f;
constexpr float SCALE = 0.044194173824159216f; // 512^-0.5

__device__ inline void fma4(float4& a, const float4& w, float s) {
    a.x += w.x * s; a.y += w.y * s; a.z += w.z * s; a.w += w.w * s;
}

__device__ inline float wave_sum(float x) {
#pragma unroll
    for (int off = 32; off; off >>= 1) x += __shfl_xor(x, off, 64);
    return x;
}

__device__ inline void wave_argmin(float& d, int& i) {
#pragma unroll
    for (int off = 32; off; off >>= 1) {
        float od = __shfl_xor(d, off, 64);
        int   oi = __shfl_xor(i, off, 64);
        if (od < d || (od == d && oi < i)) { d = od; i = oi; }
    }
}

// ================= verified round-2 GEMM body (64t x 64j, dbuf, 1 barrier/chunk) =====
// X: [256][1024] t-major. WT: [1024][N] k-major. P[slot][256][N].
// sX/sW: [2][2176] each (LDT=68). LDS total 34816 B.
__device__ __forceinline__ void d_gemmT(const float* __restrict__ WT,
                                        const float* __restrict__ X,
                                        float* __restrict__ P, int N,
                                        int j0, int t0, int k0, int NC, int slot,
                                        float* __restrict__ sX, float* __restrict__ sW) {
    constexpr int LDT = 68;
    int tid = threadIdx.x;
    int jq = tid & 15;
    int tq = tid >> 4;
    int f0 = tid * 2, f1 = tid * 2 + 1;
    int tA0 = f0 >> 3, kqA0 = f0 & 7;
    int tA1 = f1 >> 3, kqA1 = f1 & 7;
    int kwB0 = f0 >> 4, jB0 = f0 & 15;
    int kwB1 = f1 >> 4, jB1 = f1 & 15;
    float4 vx0, vx1, vw0, vw1;

#define GLOAD(kbase) do { \
        vx0 = *(const float4*)&X[(size_t)(t0 + tA0) * D2 + (kbase) + kqA0 * 4]; \
        vx1 = *(const float4*)&X[(size_t)(t0 + tA1) * D2 + (kbase) + kqA1 * 4]; \
        vw0 = *(const float4*)&WT[(size_t)((kbase) + kwB0) * N + j0 + jB0 * 4]; \
        vw1 = *(const float4*)&WT[(size_t)((kbase) + kwB1) * N + j0 + jB1 * 4]; \
    } while (0)
#define LSTORE(bufi) do { \
        float* sxB = sX + (bufi) * 2176; float* swB = sW + (bufi) * 2176; \
        sxB[(kqA0 * 4 + 0) * LDT + tA0] = vx0.x; \
        sxB[(kqA0 * 4 + 1) * LDT + tA0] = vx0.y; \
        sxB[(kqA0 * 4 + 2) * LDT + tA0] = vx0.z; \
        sxB[(kqA0 * 4 + 3) * LDT + tA0] = vx0.w; \
        sxB[(kqA1 * 4 + 0) * LDT + tA1] = vx1.x; \
        sxB[(kqA1 * 4 + 1) * LDT + tA1] = vx1.y; \
        sxB[(kqA1 * 4 + 2) * LDT + tA1] = vx1.z; \
        sxB[(kqA1 * 4 + 3) * LDT + tA1] = vx1.w; \
        *(float4*)&swB[kwB0 * LDT + jB0 * 4] = vw0; \
        *(float4*)&swB[kwB1 * LDT + jB1 * 4] = vw1; \
    } while (0)

    float4 acc0 = {0,0,0,0}, acc1 = {0,0,0,0}, acc2 = {0,0,0,0}, acc3 = {0,0,0,0};

    GLOAD(k0);
    LSTORE(0);
    __syncthreads();

    for (int kc = 0; kc < NC; ++kc) {
        if (kc + 1 < NC) GLOAD(k0 + (kc + 1) * 32);
        const float* sxB = sX + (kc & 1) * 2176;
        const float* swB = sW + (kc & 1) * 2176;
#pragma unroll 8
        for (int k = 0; k < 32; ++k) {
            float4 xa = *(const float4*)&sxB[k * LDT + tq * 4];
            float4 wb = *(const float4*)&swB[k * LDT + jq * 4];
            fma4(acc0, wb, xa.x);
            fma4(acc1, wb, xa.y);
            fma4(acc2, wb, xa.z);
            fma4(acc3, wb, xa.w);
        }
        if (kc + 1 < NC) LSTORE((kc + 1) & 1);
        __syncthreads();
    }
#undef GLOAD
#undef LSTORE

    size_t base = ((size_t)slot * NTOK + (t0 + tq * 4)) * N + j0 + jq * 4;
    *(float4*)&P[base]         = acc0;
    *(float4*)&P[base + N]     = acc1;
    *(float4*)&P[base + 2*N]   = acc2;
    *(float4*)&P[base + 3*N]   = acc3;
}

// generic GEMM launch: grid (N/64, 4, S); K-slice = KB per z-slot
template<int KB>
__global__ __launch_bounds__(256) void gemmT_kernel(const float* __restrict__ WT,
                                                    const float* __restrict__ X,
                                                    float* __restrict__ P,
                                                    int N) {
    __shared__ __align__(16) float sX[2 * 2176];
    __shared__ __align__(16) float sW[2 * 2176];
    d_gemmT(WT, X, P, N, blockIdx.x * 64, blockIdx.y * 64,
            blockIdx.z * KB, KB / 32, blockIdx.z, sX, sW);
}

// merged cell + KV gemm (both read the same X): flat grid 896.
// blocks [0,512): cell — 64 tiles (16j x 4t) x 8 splits, NC=4.
// blocks [512,896): KV — 96 tiles (24j x 4t) x 4 splits, NC=8, N=1536.
__global__ __launch_bounds__(256) void cellkv_kernel(const float* __restrict__ CW,
                                                     const float* __restrict__ KVT,
                                                     const float* __restrict__ X,
                                                     float* __restrict__ cellP,
                                                     float* __restrict__ kvP) {
    __shared__ __align__(16) float sX[2 * 2176];
    __shared__ __align__(16) float sW[2 * 2176];
    int b = blockIdx.x;
    if (b < 512) {
        int s = b & 7, tile = b >> 3;
        int jx = tile & 15, tx = tile >> 4;
        d_gemmT(CW, X, cellP, D2, jx * 64, tx * 64, s * 128, 4, s, sX, sW);
    } else {
        int q = b - 512;
        int s = q & 3, tile = q >> 2;          // tile in [0,96)
        int jx = tile % 24, tx = tile / 24;
        d_gemmT(KVT, X, kvP, 1536, jx * 64, tx * 64, s * 256, 8, s, sX, sW);
    }
}

// ---------------- merged cell epilogue (bx<2) + KV combine slot (bx>=2) ----------------
// grid (8, 256) with doKV=1, or (2,256) with doKV=0. block 256.
__global__ __launch_bounds__(256) void epikv_kernel(const float* __restrict__ cellP,
                                                    float* __restrict__ z,
                                                    const float* __restrict__ kvP,
                                                    const float* __restrict__ kb,
                                                    const float* __restrict__ vb,
                                                    float* __restrict__ Kslot,
                                                    float* __restrict__ Vslot,
                                                    int doKV) {
    int bx = blockIdx.x, t = blockIdx.y, tid = threadIdx.x;
    if (bx < 2) {
        int j = bx * 256 + tid;
        float lr = 0.f, li = 0.f;
#pragma unroll
        for (int s = 0; s < 8; ++s) {
            lr += cellP[((size_t)s * NTOK + t) * D2 + j];
            li += cellP[((size_t)s * NTOK + t) * D2 + DD + j];
        }
        float m = sqrtf(lr * lr + li * li + EPSF);
        float inv = 1.0f / (1.0f + m);
        z[(size_t)t * D2 + j]      = tanhf(lr * inv);
        z[(size_t)t * D2 + DD + j] = tanhf(li * inv);
    } else if (doKV) {
        int e = (bx - 2) * 256 + tid;
        float v = 0.f;
#pragma unroll
        for (int s = 0; s < 4; ++s)
            v += kvP[((size_t)s * NTOK + t) * 1536 + e];
        if (e < DD) Kslot[(size_t)t * DD + e]        = v + kb[e];
        else        Vslot[(size_t)t * D2 + (e - DD)] = v + vb[e - DD];
    }
}

// ---------------- attend: wave-shuffle reduce, softmax, ctx (8 QP partials) ----------------
__global__ __launch_bounds__(256) void attend8_kernel(float* __restrict__ z,
                                                      const float* __restrict__ QP,
                                                      const float* __restrict__ qb,
                                                      const float* __restrict__ Kmem,
                                                      const float* __restrict__ Vmem,
                                                      const float* __restrict__ conf,
                                                      int M) {
    int v = blockIdx.x, tid = threadIdx.x;
    int lane = tid & 63, w = tid >> 6;
    __shared__ float s_part[4][5];
    float q0 = 0.f, q1 = 0.f;
#pragma unroll
    for (int s = 0; s < 8; ++s) {
        q0 += QP[((size_t)s * NTOK + v) * DD + tid];
        q1 += QP[((size_t)s * NTOK + v) * DD + 256 + tid];
    }
    q0 += qb[tid];
    q1 += qb[256 + tid];
    float sc[5];
#pragma unroll
    for (int m = 0; m < 5; ++m) {
        if (m < M) {
            const float* K = Kmem + (size_t)m * NTOK * DD + (size_t)v * DD;
            sc[m] = q0 * K[tid] + q1 * K[256 + tid];
        } else sc[m] = 0.f;
    }
#pragma unroll
    for (int m = 0; m < 5; ++m) {
        if (m < M) {
            float x = wave_sum(sc[m]);
            if (lane == 0) s_part[w][m] = x;
        }
    }
    __syncthreads();
    float cf = conf[v];
    float scf[5];
    float mx = -1e30f;
#pragma unroll
    for (int m = 0; m < 5; ++m) {
        if (m < M) {
            float t = (s_part[0][m] + s_part[1][m] + s_part[2][m] + s_part[3][m]) * SCALE * cf;
            scf[m] = t;
            mx = fmaxf(mx, t);
        }
    }
    float sum = 0.f;
#pragma unroll
    for (int m = 0; m < 5; ++m) {
        if (m < M) { scf[m] = expf(scf[m] - mx); sum += scf[m]; }
    }
    float inv = 1.0f / sum;
#pragma unroll
    for (int r = 0; r < 4; ++r) {
        int e = r * 256 + tid;
        float ctx = 0.f;
#pragma unroll
        for (int m = 0; m < 5; ++m)
            if (m < M) ctx += scf[m] * Vmem[(size_t)m * NTOK * D2 + (size_t)v * D2 + e];
        z[(size_t)v * D2 + e] += 0.1f * ctx * inv;
    }
}

// ---------------- finish: wave-shuffle reductions, 512 threads (8 symP partials) -----
__global__ __launch_bounds__(512) void finish8_kernel(float* __restrict__ z,
                                                      const float* __restrict__ sym,
                                                      const float* __restrict__ snorm,
                                                      const float* __restrict__ con,
                                                      const float* __restrict__ conT,
                                                      const float* __restrict__ symP,
                                                      float* __restrict__ conf,
                                                      float* __restrict__ symErr,
                                                      float* __restrict__ conErr) {
    int t0 = blockIdx.x, tid = threadIdx.x;
    int lane = tid & 63, w = tid >> 6;
    __shared__ __align__(16) float s_z[D2];
    __shared__ float wA[8];
    __shared__ float wB[8]; __shared__ int wiB[8];
    __shared__ float wC[8], wD[8];
    __shared__ float wE[8];
    __shared__ int   s_ci[1];
    __shared__ float s_pd[512], s_pc[512];

    if (tid < 256) ((float4*)s_z)[tid] = ((const float4*)(z + (size_t)t0 * D2))[tid];
    __syncthreads();
    {
        float a = s_z[tid], b = s_z[512 + tid];
        float nrm = wave_sum(a * a + b * b);
        if (lane == 0) wA[w] = nrm;
    }
    __syncthreads();
    float znorm = 0.f;
#pragma unroll
    for (int k = 0; k < 8; ++k) znorm += wA[k];
    {
        float dot = 0.f;
#pragma unroll
        for (int s = 0; s < 8; ++s)
            dot += symP[((size_t)s * NTOK + t0) * NSYM + tid];
        float d = (znorm + snorm[tid]) - 2.f * dot;
        int idx = tid;
        wave_argmin(d, idx);
        if (lane == 0) { wB[w] = d; wiB[w] = idx; }
    }
    __syncthreads();
    float dmin = wB[0]; int si = wiB[0];
#pragma unroll
    for (int k = 1; k < 8; ++k) {
        if (wB[k] < dmin || (wB[k] == dmin && wiB[k] < si)) { dmin = wB[k]; si = wiB[k]; }
    }
    if (tid == 0) conf[t0] = 1.0f / (1.0f + dmin);
    {
        const float* crow = sym + (size_t)si * D2;
        float errp = 0.f, zn2 = 0.f;
#pragma unroll
        for (int r = 0; r < 2; ++r) {
            int e = r * 512 + tid;
            float zf = s_z[e];
            float diff = crow[e] - zf;
            errp += diff * diff;
            float zn = zf + diff;
            zn2 += zn * zn;
            s_z[e] = zn;
            z[(size_t)t0 * D2 + e] = zn;
        }
        errp = wave_sum(errp);
        zn2  = wave_sum(zn2);
        if (lane == 0) { wC[w] = errp; wD[w] = zn2; }
    }
    __syncthreads();
    if (tid == 0) {
        float s = 0.f;
#pragma unroll
        for (int k = 0; k < 8; ++k) s += wC[k];
        symErr[t0] += s;
    }
    float zsnorm = 0.f;
#pragma unroll
    for (int k = 0; k < 8; ++k) zsnorm += wD[k];
    {
        int c = tid & 63, sl = tid >> 6;
        float pd = 0.f, pc = 0.f;
        int kk0 = sl * 128;
#pragma unroll 4
        for (int k = kk0; k < kk0 + 128; ++k) {
            float wv = conT[(size_t)k * NCON + c];
            pd += wv * s_z[k];
            pc += wv * wv;
        }
        s_pd[tid] = pd; s_pc[tid] = pc;
    }
    __syncthreads();
    if (tid < 64) {
        float dot2 = 0.f, cn2 = 0.f;
#pragma unroll
        for (int i = 0; i < 8; ++i) { dot2 += s_pd[tid + 64 * i]; cn2 += s_pc[tid + 64 * i]; }
        float dc = (zsnorm + cn2) - 2.f * dot2;
        int ic = tid;
        wave_argmin(dc, ic);
        if (tid == 0) s_ci[0] = ic;
    }
    __syncthreads();
    int ci0 = s_ci[0];
    {
        const float* crow = con + (size_t)ci0 * D2;
        float p = 0.f;
#pragma unroll
        for (int r = 0; r < 2; ++r) {
            int e = r * 512 + tid;
            float diff = crow[e] - s_z[e];
            p += diff * diff;
        }
        p = wave_sum(p);
        if (lane == 0) wE[w] = p;
    }
    __syncthreads();
    if (tid == 0) {
        float s = 0.f;
#pragma unroll
        for (int k = 0; k < 8; ++k) s += wE[k];
        conErr[t0] += s;
    }
}

// ---------------- dec combine: rows = sum of 16 partials + dec_b ----------------
__global__ void deccomb_kernel(const float* __restrict__ P, const float* __restrict__ db,
                               float* __restrict__ rows) {
    int t = blockIdx.x, j = threadIdx.x;
    float v = 0.f;
#pragma unroll
    for (int s = 0; s < 16; ++s)
        v += P[((size_t)s * NTOK + t) * VOCAB + j];
    rows[(size_t)t * VOCAB + j] = v + db[j];
}

// ---------------- scatter + fused loss (last block) ----------------
__global__ __launch_bounds__(256) void scatter_kernel(const int* __restrict__ x,
                                                      const float* __restrict__ rows,
                                                      float* __restrict__ out,
                                                      const int* __restrict__ hist,
                                                      const float* __restrict__ symErr,
                                                      const float* __restrict__ conErr) {
    int tid = threadIdx.x;
    if (blockIdx.x == BS_TOT / 4) {
        __shared__ double rs[256], rc[256];
        rs[tid] = (double)hist[tid] * (double)symErr[tid];
        rc[tid] = (double)hist[tid] * (double)conErr[tid];
        __syncthreads();
        for (int off = 128; off > 0; off >>= 1) {
            if (tid < off) { rs[tid] += rs[tid + off]; rc[tid] += rc[tid + off]; }
            __syncthreads();
        }
        if (tid == 0) {
            const double denom = (double)BS_TOT * (double)D2;
            out[(size_t)BS_TOT * VOCAB]     = (float)(1.25 * rs[0] / denom);
            out[(size_t)BS_TOT * VOCAB + 1] = (float)(1.25 * rc[0] / denom);
        }
        return;
    }
    int pos = blockIdx.x * 4 + (tid >> 6);
    int lane = tid & 63;
    int v = x[pos];
    const float4* r = (const float4*)(rows + (size_t)v * VOCAB);
    ((float4*)(out + (size_t)pos * VOCAB))[lane] = r[lane];
}

// ---------------- batched setup: 6 transposes + zero-init ----------------
__global__ void tbatch_kernel(const float* __restrict__ qw, const float* __restrict__ kw,
                              const float* __restrict__ vw, const float* __restrict__ sym,
                              const float* __restrict__ dec_w, const float* __restrict__ con,
                              float* __restrict__ qwT, float* __restrict__ KVT,
                              float* __restrict__ symT, float* __restrict__ decT,
                              float* __restrict__ conT,
                              float* __restrict__ symErr, float* __restrict__ conErr,
                              int* __restrict__ hist) {
    int b = blockIdx.x;
    const float* in; float* out; int ldo;
    if      (b < 512)  {           in = qw;    out = qwT;      ldo = DD;    }
    else if (b < 1024) { b -= 512; in = kw;    out = KVT;      ldo = 1536;  }
    else if (b < 2048) { b -= 1024; in = vw;   out = KVT + DD; ldo = 1536;  }
    else if (b < 2560) { b -= 2048; in = sym;  out = symT;     ldo = NSYM;  }
    else if (b < 2816) { b -= 2560; in = dec_w; out = decT;    ldo = VOCAB; }
    else if (b < 2880) { b -= 2816; in = con;  out = conT;     ldo = NCON;  }
    else {
        int t = threadIdx.y * 32 + threadIdx.x;  // 256 threads
        symErr[t] = 0.f; conErr[t] = 0.f; hist[t] = 0;
        return;
    }
    __shared__ float t[32][33];
    int bx = b & 31, by = b >> 5;
    int c0 = bx * 32, r0 = by * 32;
    int x = threadIdx.x, y = threadIdx.y;
#pragma unroll
    for (int i = 0; i < 32; i += 8)
        t[y + i][x] = in[(size_t)(r0 + y + i) * D2 + c0 + x];
    __syncthreads();
#pragma unroll
    for (int i = 0; i < 32; i += 8)
        out[(size_t)(c0 + y + i) * ldo + r0 + x] = t[x][y + i];
}

__global__ void hist_kernel(const int* __restrict__ x, int* __restrict__ hist) {
    int i = blockIdx.x * 256 + threadIdx.x;
    atomicAdd(&hist[x[i]], 1);
}

// ---------------- build combined cell weight CW[1024][1024] ----------------
__global__ void buildcw_kernel(const float* __restrict__ Wr, const float* __restrict__ Wi,
                               float* __restrict__ CW) {
    __shared__ float tr[32][33], ti[32][33];
    int j0 = blockIdx.x * 32, k0 = blockIdx.y * 32;
    int x = threadIdx.x, y = threadIdx.y;
#pragma unroll
    for (int i = 0; i < 32; i += 8) {
        tr[y + i][x] = Wr[(size_t)(j0 + y + i) * DD + k0 + x];
        ti[y + i][x] = Wi[(size_t)(j0 + y + i) * DD + k0 + x];
    }
    __syncthreads();
#pragma unroll
    for (int i = 0; i < 32; i += 8) {
        float vr = tr[x][y + i];
        float vi = ti[x][y + i];
        int k = k0 + y + i, j = j0 + x;
        CW[(size_t)k * D2 + j]                    = vr;
        CW[(size_t)k * D2 + DD + j]               = vi;
        CW[(size_t)(DD + k) * D2 + j]             = -vi;
        CW[(size_t)(DD + k) * D2 + DD + j]        = vr;
    }
}

// ---------------- embed (blocks 0..255) + sym norms (blocks 256..767), block 512 ----------------
__global__ __launch_bounds__(512) void symembed_kernel(const float* __restrict__ mag,
                                                       const float* __restrict__ phase,
                                                       const float* __restrict__ sym,
                                                       float* __restrict__ dst,
                                                       float* __restrict__ snorm) {
    int bid = blockIdx.x, tid = threadIdx.x;
    if (bid < NTOK) {
        int v = bid, j = tid;
        float r = mag[v * DD + j], t = phase[v * DD + j];
        dst[(size_t)v * D2 + j]      = r * cosf(t);
        dst[(size_t)v * D2 + DD + j] = r * sinf(t);
        return;
    }
    int c = bid - NTOK;
    float2 vv = ((const float2*)(sym + (size_t)c * D2))[tid];
    float p = vv.x * vv.x + vv.y * vv.y;
    p = wave_sum(p);
    __shared__ float s_w[8];
    int lane = tid & 63, w = tid >> 6;
    if (lane == 0) s_w[w] = p;
    __syncthreads();
    if (tid == 0) {
        float s = 0.f;
#pragma unroll
        for (int k = 0; k < 8; ++k) s += s_w[k];
        snorm[c] = s;
    }
}

// ---------------- host ----------------
extern "C" void kernel_launch(void* const* d_in, const int* in_sizes, int n_in,
                              void* d_out, int out_size, void* d_ws, size_t ws_size,
                              hipStream_t stream) {
    const int*   x     = (const int*)  d_in[0];
    const float* mag   = (const float*)d_in[1];
    const float* phase = (const float*)d_in[2];
    const float* Wr    = (const float*)d_in[3];
    const float* Wi    = (const float*)d_in[4];
    const float* qw    = (const float*)d_in[5];
    const float* qb    = (const float*)d_in[6];
    const float* kw    = (const float*)d_in[7];
    const float* kb    = (const float*)d_in[8];
    const float* vw    = (const float*)d_in[9];
    const float* vb    = (const float*)d_in[10];
    const float* dec_w = (const float*)d_in[11];
    const float* dec_b = (const float*)d_in[12];
    const float* sym   = (const float*)d_in[13];
    const float* con   = (const float*)d_in[14];
    float* out = (float*)d_out;

    // workspace layout (floats); total ~42.5 MB
    float* ws     = (float*)d_ws;
    float* bufA   = ws;                          // 256*1024
    float* bufB   = bufA + NTOK * D2;            // 256*1024
    float* Kmem   = bufB + NTOK * D2;            // 6*256*512
    float* Vmem   = Kmem + NDEPTH * NTOK * DD;   // 6*256*1024
    float* rows   = Vmem + NDEPTH * NTOK * D2;   // 256*256
    float* CW     = rows + NTOK * VOCAB;         // 1024*1024
    float* qwT    = CW + D2 * D2;                // 1024*512
    float* KVT    = qwT + D2 * DD;               // 1024*1536
    float* symT   = KVT + D2 * 1536;             // 1024*512
    float* decT   = symT + D2 * NSYM;            // 1024*256
    float* conT   = decT + D2 * VOCAB;           // 1024*64
    float* bigP   = conT + D2 * NCON;            // 2,097,152 floats
    float* kvP    = bigP + 8 * NTOK * D2;        // 4*256*1536
    float* snorm  = kvP + 4 * NTOK * 1536;       // 512
    float* conf   = snorm + NSYM;                // 256
    float* symErr = conf + NTOK;                 // 256
    float* conErr = symErr + NTOK;               // 256
    int*   hist   = (int*)(conErr + NTOK);       // 256

    float* QP   = bigP;                 // 8*256*512
    float* symP = bigP + 1048576;       // 8*256*512
    float* decP = bigP;                 // 16*256*256

    dim3 tb(32, 8);
    tbatch_kernel<<<2881, tb, 0, stream>>>(qw, kw, vw, sym, dec_w, con,
                                           qwT, KVT, symT, decT, conT,
                                           symErr, conErr, hist);
    buildcw_kernel<<<dim3(16, 16), tb, 0, stream>>>(Wr, Wi, CW);
    hist_kernel<<<BS_TOT / 256, 256, 0, stream>>>(x, hist);
    symembed_kernel<<<NTOK + NSYM, 512, 0, stream>>>(mag, phase, sym, bufA, snorm);

    float* cur = bufA;
    float* oth = bufB;
    for (int d = 0; d < NDEPTH; ++d) {
        if (d == 0) {
            gemmT_kernel<128><<<dim3(16, 4, 8), 256, 0, stream>>>(CW, cur, bigP, D2);
            epikv_kernel<<<dim3(2, 256), 256, 0, stream>>>(bigP, oth, kvP, kb, vb,
                                                           Kmem, Vmem, 0);
        } else {
            // cell(d) + KV(slot d-1) share the same input `cur`
            cellkv_kernel<<<896, 256, 0, stream>>>(CW, KVT, cur, bigP, kvP);
            epikv_kernel<<<dim3(8, 256), 256, 0, stream>>>(
                bigP, oth, kvP, kb, vb,
                Kmem + (size_t)(d - 1) * NTOK * DD,
                Vmem + (size_t)(d - 1) * NTOK * D2, 1);
        }
        { float* t = cur; cur = oth; oth = t; }
        if (d > 0) {
            gemmT_kernel<128><<<dim3(8, 4, 8), 256, 0, stream>>>(qwT, cur, QP, DD);
            attend8_kernel<<<NTOK, 256, 0, stream>>>(cur, QP, qb, Kmem, Vmem, conf, d);
        }
        gemmT_kernel<128><<<dim3(8, 4, 8), 256, 0, stream>>>(symT, cur, symP, NSYM);
        finish8_kernel<<<NTOK, 512, 0, stream>>>(cur, sym, snorm, con, conT, symP,
                                                 conf, symErr, conErr);
    }
    for (int l = 0; l < NLOOK; ++l) {
        gemmT_kernel<128><<<dim3(16, 4, 8), 256, 0, stream>>>(CW, cur, bigP, D2);
        epikv_kernel<<<dim3(2, 256), 256, 0, stream>>>(bigP, oth, kvP, kb, vb,
                                                       Kmem, Vmem, 0);
        { float* t = cur; cur = oth; oth = t; }
    }
    gemmT_kernel<64><<<dim3(4, 4, 16), 256, 0, stream>>>(decT, cur, decP, VOCAB);
    deccomb_kernel<<<256, 256, 0, stream>>>(decP, dec_b, rows);
    scatter_kernel<<<BS_TOT / 4 + 1, 256, 0, stream>>>(x, rows, out, hist, symErr, conErr);
}